// Round 20
// baseline (221.372 us; speedup 1.0000x reference)
//
#include <hip/hip_runtime.h>
#include <hip/hip_fp16.h>

// Attention: ctx,W = softmax(Q K^T / 32 + mask, padmask) @ V
// B=8, QL=KL=2048, D=1024, fp32 I/O. fp16 MFMA internally (no fp32 MFMA on CDNA4).
// R12: PV K-compaction. R13/14: scores N-compaction. R15: fused cvt+vt.
// R16: qkc tail-tile split. R18/19: NT stores/loads for stream L2 hygiene.
// R20: dynamic mask-zero detection -- softmax skips 128 MB of logical mask
//      reads when attn_mask is all-zero (exact for all inputs; verified
//      on-device each call via prep's extra blocks + atomicOr flag).
#define B_ 8
#define QL_ 2048
#define KL_ 2048
#define D_ 1024

typedef _Float16 f16x8 __attribute__((ext_vector_type(8)));
typedef _Float16 f16x4 __attribute__((ext_vector_type(4)));
typedef float f32x4 __attribute__((ext_vector_type(4)));

// ---------------------------------------------------------------- async 16B
__device__ __forceinline__ void async16(const void* g, void* l) {
  __builtin_amdgcn_global_load_lds(
      (const __attribute__((address_space(1))) unsigned int*)g,
      (__attribute__((address_space(3))) unsigned int*)l, 16, 0, 0);
}

// ------------------------------------------- prefix scan + mask-zero check
// Blocks 0..7: per-batch pad scan (pos/inv/kcp). Blocks 8..2055: scan the
// 16 MB attn_mask (NT loads); any nonzero -> atomicOr(mz,1). mz was
// memset-to-0 on-stream before this kernel.
__global__ __launch_bounds__(256) void prep_k(const int* __restrict__ pad,
                                              int* __restrict__ pos,
                                              int* __restrict__ inv,
                                              int* __restrict__ kcp,
                                              const float* __restrict__ mask,
                                              int* __restrict__ mz) {
  if (blockIdx.x >= B_) {
    const int mb = blockIdx.x - B_;
    const f32x4* mp = reinterpret_cast<const f32x4*>(mask);
    const int i = (mb * 256 + threadIdx.x) * 2;
    f32x4 a = __builtin_nontemporal_load(mp + i);
    f32x4 c = __builtin_nontemporal_load(mp + i + 1);
    const bool nz = (a[0] != 0.0f) | (a[1] != 0.0f) | (a[2] != 0.0f) |
                    (a[3] != 0.0f) | (c[0] != 0.0f) | (c[1] != 0.0f) |
                    (c[2] != 0.0f) | (c[3] != 0.0f);
    if (nz) atomicOr(mz, 1);
    return;
  }
  const int b = blockIdx.x;
  const int t = threadIdx.x;
  const int lane = t & 63, wv = t >> 6;
  __shared__ int wsum[4], wpre[4], kc_sh;
  const int* pr = pad + b * KL_;
  int* po = pos + b * KL_;
  int* iv = inv + b * KL_;
  int c[8], loc = 0;
#pragma unroll
  for (int j = 0; j < 8; ++j) {
    c[j] = (pr[t * 8 + j] == 0);
    loc += c[j];
  }
  int inc = loc;  // inclusive scan across the wave
  for (int d = 1; d < 64; d <<= 1) {
    int v = __shfl_up(inc, d);
    if (lane >= d) inc += v;
  }
  if (lane == 63) wsum[wv] = inc;
  __syncthreads();
  if (t == 0) {
    int acc = 0;
    for (int w = 0; w < 4; ++w) {
      wpre[w] = acc;
      acc += wsum[w];
    }
    kc_sh = acc;
    kcp[b] = (acc == 0) ? KL_ : acc;
  }
  __syncthreads();
  const int kc = kc_sh;
  int base = wpre[wv] + inc - loc;  // exclusive prefix for this thread
#pragma unroll
  for (int j = 0; j < 8; ++j) {
    const int k = t * 8 + j;
    if (kc == 0) {
      po[k] = k;
      iv[k] = k;
    } else {
      po[k] = base;
      if (c[j]) iv[base] = k;
    }
    base += c[j];
  }
}

// --------------------------------------------- fused cvt (Q,K) + V transpose
__global__ __launch_bounds__(256) void cvtvt_k(
    const float* __restrict__ Q, const float* __restrict__ K,
    const float* __restrict__ V, _Float16* __restrict__ Qh,
    _Float16* __restrict__ Khc, _Float16* __restrict__ VTc,
    const int* __restrict__ pad, const int* __restrict__ pos) {
  constexpr int CVT = B_ * QL_ * D_ / 8 / 256;  // 8192 blocks per tensor
  __shared__ float tile[32][33];
  const int id = blockIdx.x;
  if (id < 2 * CVT) {
    const bool isQ = id < CVT;
    const int i = (isQ ? id : id - CVT) * 256 + threadIdx.x;
    const f32x4* src = reinterpret_cast<const f32x4*>(isQ ? Q : K);
    const float scale = isQ ? 0.03125f : 1.0f;
    // Q/K are read exactly once -> bypass L2 (R19)
    f32x4 a = __builtin_nontemporal_load(src + i * 2);
    f32x4 b = __builtin_nontemporal_load(src + i * 2 + 1);
    f16x8 h;
    h[0] = (_Float16)(a[0] * scale); h[1] = (_Float16)(a[1] * scale);
    h[2] = (_Float16)(a[2] * scale); h[3] = (_Float16)(a[3] * scale);
    h[4] = (_Float16)(b[0] * scale); h[5] = (_Float16)(b[1] * scale);
    h[6] = (_Float16)(b[2] * scale); h[7] = (_Float16)(b[3] * scale);
    if (isQ) {
      reinterpret_cast<f16x8*>(Qh)[i] = h;
    } else {
      const int gk = (i * 8) >> 10;  // global K row (b*2048 + k)
      const int col8 = i & 127;      // 8-elem chunk within the row
      if (pad[gk] == 0) {
        const int b2 = gk >> 11;
        const int prow = pos[gk];  // packed row within batch
        reinterpret_cast<f16x8*>(Khc)[(size_t)(b2 << 11 | prow) * 128 + col8] =
            h;
      }
    }
  } else {
    const int vid = id - 2 * CVT;
    const int k0 = (vid & 63) * 32;         // KL/32 = 64
    const int d0 = ((vid >> 6) & 31) * 32;  // D/32 = 32
    const int b = vid >> 11;
    const float* Vb = V + (size_t)b * KL_ * D_;
    _Float16* VTb = VTc + (size_t)b * D_ * KL_;
    const int c = threadIdx.x & 31, r = threadIdx.x >> 5;
#pragma unroll
    for (int s = 0; s < 4; ++s)
      tile[r + s * 8][c] = __builtin_nontemporal_load(
          &Vb[(size_t)(k0 + r + s * 8) * D_ + d0 + c]);
    __syncthreads();
    const int kk = k0 + c;
    const int keep = (pad[b * KL_ + kk] == 0);
    const int col = pos[b * KL_ + kk];
#pragma unroll
    for (int s = 0; s < 4; ++s)
      if (keep)
        VTb[(size_t)(d0 + r + s * 8) * KL_ + col] =
            (_Float16)tile[c][r + s * 8];
  }
}

// ---------------------------------------------------------------- fallbacks
__global__ __launch_bounds__(256) void cvt2_k(const float* __restrict__ Q,
                                              const float* __restrict__ K,
                                              _Float16* __restrict__ Qh,
                                              _Float16* __restrict__ Kh) {
  constexpr int HALF = B_ * QL_ * D_ / 8 / 256;
  const bool isQ = blockIdx.x < HALF;
  const int i = (isQ ? blockIdx.x : blockIdx.x - HALF) * 256 + threadIdx.x;
  const float4* src = reinterpret_cast<const float4*>(isQ ? Q : K);
  const float scale = isQ ? 0.03125f : 1.0f;
  float4 a = src[i * 2], b = src[i * 2 + 1];
  f16x8 h;
  h[0] = (_Float16)(a.x * scale); h[1] = (_Float16)(a.y * scale);
  h[2] = (_Float16)(a.z * scale); h[3] = (_Float16)(a.w * scale);
  h[4] = (_Float16)(b.x * scale); h[5] = (_Float16)(b.y * scale);
  h[6] = (_Float16)(b.z * scale); h[7] = (_Float16)(b.w * scale);
  reinterpret_cast<f16x8*>(isQ ? Qh : Kh)[i] = h;
}

__global__ __launch_bounds__(256) void vt_k(const float* __restrict__ V,
                                            _Float16* __restrict__ VT) {
  __shared__ float tile[32][33];
  const int k0 = blockIdx.x * 32, d0 = blockIdx.y * 32, b = blockIdx.z;
  const float* Vb = V + (size_t)b * KL_ * D_;
  _Float16* VTb = VT + (size_t)b * D_ * KL_;
  const int c = threadIdx.x & 31, r = threadIdx.x >> 5;
#pragma unroll
  for (int s = 0; s < 4; ++s)
    tile[r + s * 8][c] = Vb[(size_t)(k0 + r + s * 8) * D_ + d0 + c];
  __syncthreads();
#pragma unroll
  for (int s = 0; s < 4; ++s)
    VTb[(size_t)(d0 + r + s * 8) * KL_ + k0 + c] = (_Float16)tile[c][r + s * 8];
}

// ---------------------------------------------------------------- dense GEMM
template <bool SCORES>
__global__ __launch_bounds__(512, 2) void fgemm_k(
    const _Float16* __restrict__ Ah, const _Float16* __restrict__ Bh,
    float* __restrict__ Cf, _Float16* __restrict__ Ch) {
  constexpr int Mc = 2048;
  constexpr int Nc = SCORES ? 2048 : 1024;
  constexpr int Kc = SCORES ? 1024 : 2048;
  constexpr int NIT = Kc / 64;
  constexpr int GX = Mc / 256, GY = Nc / 256;
  constexpr int CPX = B_ * GX * GY / 8;

  extern __shared__ char lds[];

  const int t = threadIdx.x;
  const int lane = t & 63;
  const int wid = t >> 6;
  const int wr = wid >> 2, wc = wid & 3;
  const int lo = lane & 15, hi = lane >> 4;

  const int id = blockIdx.x;
  const int swz = (id & 7) * CPX + (id >> 3);
  const int b = swz / (GX * GY);
  const int rem = swz % (GX * GY);
  const int m0 = (rem / GY) * 256, n0 = (rem % GY) * 256;

  const _Float16* Ab = Ah + (size_t)b * Mc * Kc;
  const _Float16* Bb = Bh + (size_t)b * Nc * Kc;

  int aoff[4], boff[4], ldst[4];
#pragma unroll
  for (int j = 0; j < 4; ++j) {
    const int row = j * 64 + wid * 8 + (lane >> 3);
    const int cg = (lane & 7) ^ (lane >> 3);
    aoff[j] = (m0 + row) * Kc + cg * 8;
    boff[j] = (n0 + row) * Kc + cg * 8;
    ldst[j] = j * 8192 + wid * 1024;
  }

  auto stage = [&](int it, int slot) {
    char* base = lds + slot * 65536;
    const int kb = it * 64;
#pragma unroll
    for (int j = 0; j < 4; ++j) {
      async16(Ab + aoff[j] + kb, base + ldst[j]);
      async16(Bb + boff[j] + kb, base + 32768 + ldst[j]);
    }
  };

  f32x4 acc[8][4];
#pragma unroll
  for (int m = 0; m < 8; ++m)
#pragma unroll
    for (int n = 0; n < 4; ++n)
#pragma unroll
      for (int i = 0; i < 4; ++i) acc[m][n][i] = 0.0f;

  int raf[8], rbf_[4];
#pragma unroll
  for (int m = 0; m < 8; ++m) {
    const int r = wr * 128 + m * 16 + lo;
    raf[m] = r * 128 + ((hi ^ (r & 7)) << 4);
  }
#pragma unroll
  for (int n = 0; n < 4; ++n) {
    const int r = wc * 64 + n * 16 + lo;
    rbf_[n] = r * 128 + ((hi ^ (r & 7)) << 4);
  }

  auto compute = [&](int slot) {
    const char* Ac = lds + slot * 65536;
    const char* Bc = Ac + 32768;
#pragma unroll
    for (int kh = 0; kh < 2; ++kh) {
      const int kx = kh * 64;
      f16x8 af[8], bfr[4];
#pragma unroll
      for (int m = 0; m < 8; ++m)
        af[m] = *reinterpret_cast<const f16x8*>(Ac + (raf[m] ^ kx));
#pragma unroll
      for (int n = 0; n < 4; ++n)
        bfr[n] = *reinterpret_cast<const f16x8*>(Bc + (rbf_[n] ^ kx));
      __builtin_amdgcn_s_setprio(1);
#pragma unroll
      for (int m = 0; m < 8; ++m)
#pragma unroll
        for (int n = 0; n < 4; ++n)
          acc[m][n] = __builtin_amdgcn_mfma_f32_16x16x32_f16(
              af[m], bfr[n], acc[m][n], 0, 0, 0);
      __builtin_amdgcn_s_setprio(0);
    }
  };

  stage(0, 0);
  for (int it = 0; it < NIT; ++it) {
    asm volatile("s_waitcnt vmcnt(0) lgkmcnt(0)" ::: "memory");
    __builtin_amdgcn_sched_barrier(0);
    __builtin_amdgcn_s_barrier();
    if (it + 1 < NIT) stage(it + 1, (it + 1) & 1);
    compute(it & 1);
  }

  if constexpr (SCORES) {
    _Float16* Cb = Ch + (size_t)b * Mc * Nc;
#pragma unroll
    for (int n = 0; n < 4; ++n) {
      const int col = n0 + wc * 64 + n * 16 + lo;
#pragma unroll
      for (int m = 0; m < 8; ++m) {
        const int r0 = m0 + wr * 128 + m * 16 + hi * 4;
#pragma unroll
        for (int i = 0; i < 4; ++i)
          Cb[(size_t)(r0 + i) * Nc + col] = (_Float16)acc[m][n][i];
      }
    }
  } else {
    float* Cb = Cf + (size_t)b * Mc * Nc;
#pragma unroll
    for (int n = 0; n < 4; ++n) {
      const int col = n0 + wc * 64 + n * 16 + lo;
#pragma unroll
      for (int m = 0; m < 8; ++m) {
        const int r0 = m0 + wr * 128 + m * 16 + hi * 4;
#pragma unroll
        for (int i = 0; i < 4; ++i)
          __builtin_nontemporal_store(acc[m][n][i],
                                      &Cb[(size_t)(r0 + i) * Nc + col]);
      }
    }
  }
}

// ---------------------------------------------------------------- compact QK
__global__ __launch_bounds__(512, 2) void fgemm_qkc(
    const _Float16* __restrict__ Qh, const _Float16* __restrict__ Khc,
    _Float16* __restrict__ Sh, const int* __restrict__ inv,
    const int* __restrict__ kcp) {
  constexpr int Kc = 1024;
  constexpr int NIT = Kc / 64;

  extern __shared__ char lds[];

  const int t = threadIdx.x;
  const int lane = t & 63;
  const int wid = t >> 6;
  const int lo = lane & 15, hi = lane >> 4;
  const int id = blockIdx.x;

  if (id < 256) {
    // ---------------- main: 256x256 tile, quadrants 0..3
    const int wr = wid >> 2, wc = wid & 3;
    const int b = id & 7;
    const int n0 = ((id >> 3) & 3) * 256;
    const int m0 = ((id >> 5) & 7) * 256;

    const int kc = kcp[b];
    if (n0 >= ((kc + 63) & ~63)) return;

    const _Float16* Ab = Qh + (size_t)b * 2048 * Kc;
    const _Float16* Bb = Khc + (size_t)b * 2048 * Kc;

    int aoff[4], boff[4], ldst[4];
#pragma unroll
    for (int j = 0; j < 4; ++j) {
      const int row = j * 64 + wid * 8 + (lane >> 3);
      const int cg = (lane & 7) ^ (lane >> 3);
      aoff[j] = (m0 + row) * Kc + cg * 8;
      boff[j] = (n0 + row) * Kc + cg * 8;
      ldst[j] = j * 8192 + wid * 1024;
    }

    auto stage = [&](int it, int slot) {
      char* base = lds + slot * 65536;
      const int kb = it * 64;
#pragma unroll
      for (int j = 0; j < 4; ++j) {
        async16(Ab + aoff[j] + kb, base + ldst[j]);
        async16(Bb + boff[j] + kb, base + 32768 + ldst[j]);
      }
    };

    f32x4 acc[8][4];
#pragma unroll
    for (int m2 = 0; m2 < 8; ++m2)
#pragma unroll
      for (int n = 0; n < 4; ++n)
#pragma unroll
        for (int i = 0; i < 4; ++i) acc[m2][n][i] = 0.0f;

    int raf[8], rbf_[4];
#pragma unroll
    for (int m2 = 0; m2 < 8; ++m2) {
      const int r = wr * 128 + m2 * 16 + lo;
      raf[m2] = r * 128 + ((hi ^ (r & 7)) << 4);
    }
#pragma unroll
    for (int n = 0; n < 4; ++n) {
      const int r = wc * 64 + n * 16 + lo;
      rbf_[n] = r * 128 + ((hi ^ (r & 7)) << 4);
    }

    auto compute = [&](int slot) {
      const char* Ac = lds + slot * 65536;
      const char* Bc = Ac + 32768;
#pragma unroll
      for (int kh = 0; kh < 2; ++kh) {
        const int kx = kh * 64;
        f16x8 af[8], bfr[4];
#pragma unroll
        for (int m2 = 0; m2 < 8; ++m2)
          af[m2] = *reinterpret_cast<const f16x8*>(Ac + (raf[m2] ^ kx));
#pragma unroll
        for (int n = 0; n < 4; ++n)
          bfr[n] = *reinterpret_cast<const f16x8*>(Bc + (rbf_[n] ^ kx));
        __builtin_amdgcn_s_setprio(1);
#pragma unroll
        for (int m2 = 0; m2 < 8; ++m2)
#pragma unroll
          for (int n = 0; n < 4; ++n)
            acc[m2][n] = __builtin_amdgcn_mfma_f32_16x16x32_f16(
                af[m2], bfr[n], acc[m2][n], 0, 0, 0);
        __builtin_amdgcn_s_setprio(0);
      }
    };

    stage(0, 0);
    for (int it = 0; it < NIT; ++it) {
      asm volatile("s_waitcnt vmcnt(0) lgkmcnt(0)" ::: "memory");
      __builtin_amdgcn_sched_barrier(0);
      __builtin_amdgcn_s_barrier();
      if (it + 1 < NIT) stage(it + 1, (it + 1) & 1);
      compute(it & 1);
    }

    _Float16* Cb = Sh + (size_t)b * 2048 * 2048;
    const int* ivb = inv + b * KL_;
#pragma unroll
    for (int n = 0; n < 4; ++n) {
      const int ccol = n0 + wc * 64 + n * 16 + lo;
      if (ccol < kc) {
        const int dcol = ivb[ccol];
#pragma unroll
        for (int m2 = 0; m2 < 8; ++m2) {
          const int r0 = m0 + wr * 128 + m2 * 16 + hi * 4;
#pragma unroll
          for (int i = 0; i < 4; ++i)
            Cb[(size_t)(r0 + i) * 2048 + dcol] = (_Float16)acc[m2][n][i];
        }
      }
    }
  } else {
    // ---------------- tail: 128x64 tile, n0 >= 1024
    const int tid = id - 256;
    const int b = tid & 7;
    const int m0 = ((tid >> 3) & 15) * 128;
    const int n0 = 1024 + ((tid >> 7) & 15) * 64;

    const int kc = kcp[b];
    if (n0 >= ((kc + 63) & ~63)) return;

    const _Float16* Ab = Qh + (size_t)b * 2048 * Kc;
    const _Float16* Bb = Khc + (size_t)b * 2048 * Kc;

    const int cg = (lane & 7) ^ (lane >> 3);
    int aoff[2], ldstA[2];
#pragma unroll
    for (int j = 0; j < 2; ++j) {
      const int row = j * 64 + wid * 8 + (lane >> 3);
      aoff[j] = (m0 + row) * Kc + cg * 8;
      ldstA[j] = j * 8192 + wid * 1024;
    }
    const int boff0 = (n0 + wid * 8 + (lane >> 3)) * Kc + cg * 8;

    auto stage = [&](int it, int slot) {
      char* base = lds + slot * 32768;
      const int kb = it * 64;
      async16(Ab + aoff[0] + kb, base + ldstA[0]);
      async16(Ab + aoff[1] + kb, base + ldstA[1]);
      async16(Bb + boff0 + kb, base + 16384 + wid * 1024);
    };

    f32x4 acc[4];
#pragma unroll
    for (int n = 0; n < 4; ++n)
#pragma unroll
      for (int i = 0; i < 4; ++i) acc[n][i] = 0.0f;

    int rafm;
    {
      const int r = wid * 16 + lo;
      rafm = r * 128 + ((hi ^ (r & 7)) << 4);
    }
    int rbf2[4];
#pragma unroll
    for (int n = 0; n < 4; ++n) {
      const int r = n * 16 + lo;
      rbf2[n] = r * 128 + ((hi ^ (r & 7)) << 4);
    }

    auto compute = [&](int slot) {
      const char* Ac = lds + slot * 32768;
      const char* Bc = Ac + 16384;
#pragma unroll
      for (int kh = 0; kh < 2; ++kh) {
        const int kx = kh * 64;
        f16x8 af = *reinterpret_cast<const f16x8*>(Ac + (rafm ^ kx));
        f16x8 bfr[4];
#pragma unroll
        for (int n = 0; n < 4; ++n)
          bfr[n] = *reinterpret_cast<const f16x8*>(Bc + (rbf2[n] ^ kx));
        __builtin_amdgcn_s_setprio(1);
#pragma unroll
        for (int n = 0; n < 4; ++n)
          acc[n] = __builtin_amdgcn_mfma_f32_16x16x32_f16(af, bfr[n], acc[n],
                                                          0, 0, 0);
        __builtin_amdgcn_s_setprio(0);
      }
    };

    stage(0, 0);
    for (int it = 0; it < NIT; ++it) {
      asm volatile("s_waitcnt vmcnt(0) lgkmcnt(0)" ::: "memory");
      __builtin_amdgcn_sched_barrier(0);
      __builtin_amdgcn_s_barrier();
      if (it + 1 < NIT) stage(it + 1, (it + 1) & 1);
      compute(it & 1);
    }

    _Float16* Cb = Sh + (size_t)b * 2048 * 2048;
    const int* ivb = inv + b * KL_;
#pragma unroll
    for (int n = 0; n < 4; ++n) {
      const int ccol = n0 + n * 16 + lo;
      if (ccol < kc) {
        const int dcol = ivb[ccol];
        const int r0 = m0 + wid * 16 + hi * 4;
#pragma unroll
        for (int i = 0; i < 4; ++i)
          Cb[(size_t)(r0 + i) * 2048 + dcol] = (_Float16)acc[n][i];
      }
    }
  }
}

// ---------------------------------------------------------------- compact PV
__global__ __launch_bounds__(512, 2) void fgemm_pv(
    const _Float16* __restrict__ Whc, const _Float16* __restrict__ VTc,
    float* __restrict__ Cf, const int* __restrict__ kcp) {
  constexpr int Mc = 2048, Nc = 1024;
  constexpr int GX = 8, GY = 4;
  constexpr int CPX = B_ * GX * GY / 8;

  extern __shared__ char lds[];

  const int t = threadIdx.x;
  const int lane = t & 63;
  const int wid = t >> 6;
  const int wr = wid >> 2, wc = wid & 3;
  const int lo = lane & 15, hi = lane >> 4;

  const int id = blockIdx.x;
  const int swz = (id & 7) * CPX + (id >> 3);
  const int b = swz / (GX * GY);
  const int rem = swz % (GX * GY);
  const int m0 = (rem / GY) * 256, n0 = (rem % GY) * 256;

  const int kc = kcp[b];
  const int KA = (kc + 63) & ~63;
  const int NIT = KA >> 6;

  const _Float16* Ab = Whc + (size_t)b * 2048 * 2048;
  const _Float16* Bb = VTc + (size_t)b * Nc * KL_;

  int aoff[4], boff[4], ldst[4];
#pragma unroll
  for (int j = 0; j < 4; ++j) {
    const int row = j * 64 + wid * 8 + (lane >> 3);
    const int cg = (lane & 7) ^ (lane >> 3);
    aoff[j] = (m0 + row) * KA + cg * 8;
    boff[j] = (n0 + row) * KL_ + cg * 8;
    ldst[j] = j * 8192 + wid * 1024;
  }

  auto stage = [&](int it, int slot) {
    char* base = lds + slot * 65536;
    const int kb = it * 64;
#pragma unroll
    for (int j = 0; j < 4; ++j) {
      async16(Ab + aoff[j] + kb, base + ldst[j]);
      async16(Bb + boff[j] + kb, base + 32768 + ldst[j]);
    }
  };

  f32x4 acc[8][4];
#pragma unroll
  for (int m = 0; m < 8; ++m)
#pragma unroll
    for (int n = 0; n < 4; ++n)
#pragma unroll
      for (int i = 0; i < 4; ++i) acc[m][n][i] = 0.0f;

  int raf[8], rbf_[4];
#pragma unroll
  for (int m = 0; m < 8; ++m) {
    const int r = wr * 128 + m * 16 + lo;
    raf[m] = r * 128 + ((hi ^ (r & 7)) << 4);
  }
#pragma unroll
  for (int n = 0; n < 4; ++n) {
    const int r = wc * 64 + n * 16 + lo;
    rbf_[n] = r * 128 + ((hi ^ (r & 7)) << 4);
  }

  auto compute = [&](int slot) {
    const char* Ac = lds + slot * 65536;
    const char* Bc = Ac + 32768;
#pragma unroll
    for (int kh = 0; kh < 2; ++kh) {
      const int kx = kh * 64;
      f16x8 af[8], bfr[4];
#pragma unroll
      for (int m = 0; m < 8; ++m)
        af[m] = *reinterpret_cast<const f16x8*>(Ac + (raf[m] ^ kx));
#pragma unroll
      for (int n = 0; n < 4; ++n)
        bfr[n] = *reinterpret_cast<const f16x8*>(Bc + (rbf_[n] ^ kx));
      __builtin_amdgcn_s_setprio(1);
#pragma unroll
      for (int m = 0; m < 8; ++m)
#pragma unroll
        for (int n = 0; n < 4; ++n)
          acc[m][n] = __builtin_amdgcn_mfma_f32_16x16x32_f16(
              af[m], bfr[n], acc[m][n], 0, 0, 0);
      __builtin_amdgcn_s_setprio(0);
    }
  };

  stage(0, 0);
  for (int it = 0; it < NIT; ++it) {
    asm volatile("s_waitcnt vmcnt(0) lgkmcnt(0)" ::: "memory");
    __builtin_amdgcn_sched_barrier(0);
    __builtin_amdgcn_s_barrier();
    if (it + 1 < NIT) stage(it + 1, (it + 1) & 1);
    compute(it & 1);
  }

  float* Cb = Cf + (size_t)b * Mc * Nc;
#pragma unroll
  for (int n = 0; n < 4; ++n) {
    const int col = n0 + wc * 64 + n * 16 + lo;
#pragma unroll
    for (int m = 0; m < 8; ++m) {
      const int r0 = m0 + wr * 128 + m * 16 + hi * 4;
#pragma unroll
      for (int i = 0; i < 4; ++i)
        __builtin_nontemporal_store(acc[m][n][i],
                                    &Cb[(size_t)(r0 + i) * Nc + col]);
    }
  }
}

// ---------------------------------------------------------------- row softmax
template <bool COMPACT>
__global__ __launch_bounds__(256) void softmax_k(
    const _Float16* __restrict__ Sh, float* __restrict__ W,
    _Float16* __restrict__ Wh, const float* __restrict__ mask,
    const int* __restrict__ pad, const int* __restrict__ pos,
    const int* __restrict__ kcp, const int* __restrict__ mz) {
  const int row = blockIdx.x * 4 + (threadIdx.x >> 6);
  const int lane = threadIdx.x & 63;
  const int b = row >> 11, q = row & 2047;
  const f16x4* Sr = reinterpret_cast<const f16x4*>(Sh + (size_t)row * KL_);
  f32x4* Wr = reinterpret_cast<f32x4*>(W + (size_t)row * KL_);
  const float4* Mr = reinterpret_cast<const float4*>(mask + (size_t)q * KL_);
  const int4* Pr = reinterpret_cast<const int4*>(pad + (size_t)b * KL_);
  const int hasmask = mz ? *mz : 1;  // uniform; 0 => mask verified all-zero
  int4 pk[8];
  float4 v[8];
  if (hasmask) {
#pragma unroll
    for (int s = 0; s < 8; ++s) {
      f16x4 sv = __builtin_nontemporal_load(&Sr[s * 64 + lane]);
      float4 mk = Mr[s * 64 + lane];
      int4 p = Pr[s * 64 + lane];
      pk[s] = p;
      float4 x;
      x.x = p.x ? -1e12f : (float)sv[0] + mk.x;
      x.y = p.y ? -1e12f : (float)sv[1] + mk.y;
      x.z = p.z ? -1e12f : (float)sv[2] + mk.z;
      x.w = p.w ? -1e12f : (float)sv[3] + mk.w;
      v[s] = x;
    }
  } else {
#pragma unroll
    for (int s = 0; s < 8; ++s) {
      f16x4 sv = __builtin_nontemporal_load(&Sr[s * 64 + lane]);
      int4 p = Pr[s * 64 + lane];
      pk[s] = p;
      float4 x;
      x.x = p.x ? -1e12f : (float)sv[0];
      x.y = p.y ? -1e12f : (float)sv[1];
      x.z = p.z ? -1e12f : (float)sv[2];
      x.w = p.w ? -1e12f : (float)sv[3];
      v[s] = x;
    }
  }
  float mx = -3.402823466e38f;
#pragma unroll
  for (int s = 0; s < 8; ++s)
    mx = fmaxf(mx, fmaxf(fmaxf(v[s].x, v[s].y), fmaxf(v[s].z, v[s].w)));
#pragma unroll
  for (int off = 32; off > 0; off >>= 1) mx = fmaxf(mx, __shfl_xor(mx, off));
  float sum = 0.0f;
#pragma unroll
  for (int s = 0; s < 8; ++s) {
    v[s].x = __expf(v[s].x - mx);
    v[s].y = __expf(v[s].y - mx);
    v[s].z = __expf(v[s].z - mx);
    v[s].w = __expf(v[s].w - mx);
    sum += v[s].x + v[s].y + v[s].z + v[s].w;
  }
#pragma unroll
  for (int off = 32; off > 0; off >>= 1) sum += __shfl_xor(sum, off);
  const float inv = 1.0f / sum;

  if constexpr (COMPACT) {
    const int kc = kcp[b];
    const int kcpad = (kc + 63) & ~63;
    _Float16* Wc = Wh + (size_t)b * 2048 * 2048 + (size_t)q * kcpad;
    const int4* Po = reinterpret_cast<const int4*>(pos + (size_t)b * KL_);
#pragma unroll
    for (int s = 0; s < 8; ++s) {
      f32x4 o;
      o[0] = v[s].x * inv;
      o[1] = v[s].y * inv;
      o[2] = v[s].z * inv;
      o[3] = v[s].w * inv;
      // W is a terminal output (never re-read) -> bypass L2 (R18)
      __builtin_nontemporal_store(o, &Wr[s * 64 + lane]);
      int4 ps = Po[s * 64 + lane];
      if (!pk[s].x) Wc[ps.x] = (_Float16)o[0];
      if (!pk[s].y) Wc[ps.y] = (_Float16)o[1];
      if (!pk[s].z) Wc[ps.z] = (_Float16)o[2];
      if (!pk[s].w) Wc[ps.w] = (_Float16)o[3];
    }
    if (kc + lane < kcpad) Wc[kc + lane] = (_Float16)0.0f;  // zero tail
  } else {
    f16x4* Whr = reinterpret_cast<f16x4*>(Wh + (size_t)row * KL_);
#pragma unroll
    for (int s = 0; s < 8; ++s) {
      f32x4 o;
      o[0] = v[s].x * inv;
      o[1] = v[s].y * inv;
      o[2] = v[s].z * inv;
      o[3] = v[s].w * inv;
      __builtin_nontemporal_store(o, &Wr[s * 64 + lane]);
      f16x4 h;
      h[0] = (_Float16)o[0];
      h[1] = (_Float16)o[1];
      h[2] = (_Float16)o[2];
      h[3] = (_Float16)o[3];
      Whr[s * 64 + lane] = h;
    }
  }
}

// ---------------------------------------------------------------- launch
extern "C" void kernel_launch(void* const* d_in, const int* in_sizes, int n_in,
                              void* d_out, int out_size, void* d_ws,
                              size_t ws_size, hipStream_t stream) {
  const float* Q = (const float*)d_in[0];
  const float* K = (const float*)d_in[1];
  const float* V = (const float*)d_in[2];
  const float* mask = (const float*)d_in[3];
  const int* pad = (const int*)d_in[4];

  float* ctx = (float*)d_out;              // [8][2048][1024] fp32 (final)
  float* W = ctx + (size_t)B_ * QL_ * D_;  // [8][2048][2048] fp32 (final)
  _Float16* Sh = (_Float16*)d_out;         // S' fp16 reuses ctx region

  const size_t MB = 1024 * 1024;
  _Float16* VT = (_Float16*)d_ws;                     // 32 MiB
  _Float16* Qh = (_Float16*)((char*)d_ws + 32 * MB);  // 32 MiB
  _Float16* Kh = (_Float16*)((char*)d_ws + 64 * MB);  // 32 MiB (packed Khc)
  _Float16* Wh = Qh;                                  // 64 MiB, reused post-QK

  (void)hipFuncSetAttribute((const void*)fgemm_k<true>,
                            hipFuncAttributeMaxDynamicSharedMemorySize, 131072);
  (void)hipFuncSetAttribute((const void*)fgemm_k<false>,
                            hipFuncAttributeMaxDynamicSharedMemorySize, 131072);
  (void)hipFuncSetAttribute((const void*)fgemm_qkc,
                            hipFuncAttributeMaxDynamicSharedMemorySize, 131072);
  (void)hipFuncSetAttribute((const void*)fgemm_pv,
                            hipFuncAttributeMaxDynamicSharedMemorySize, 131072);

  const bool compact = ws_size >= 96 * MB + (1 << 18);
  if (compact) {
    int* pos = (int*)((char*)d_ws + 96 * MB);  // [8][2048] = 64 KiB
    int* inv = pos + B_ * KL_;                 // [8][2048] = 64 KiB
    int* kcp = inv + B_ * KL_;                 // [8]
    int* mz = kcp + B_;                        // [1] mask-nonzero flag
    (void)hipMemsetAsync(mz, 0, 4, stream);    // async on stream: graph-safe
    prep_k<<<dim3(B_ + 2048), 256, 0, stream>>>(pad, pos, inv, kcp, mask, mz);
    cvtvt_k<<<dim3(2 * 8192 + 64 * 32 * B_), 256, 0, stream>>>(
        Q, K, V, Qh, Kh, VT, pad, pos);
    fgemm_qkc<<<dim3(256 + 2048), 512, 131072, stream>>>(Qh, Kh, Sh, inv, kcp);
    softmax_k<true><<<dim3(B_ * QL_ / 4), 256, 0, stream>>>(
        Sh, W, Wh, mask, pad, pos, kcp, mz);
    fgemm_pv<<<dim3(B_ * 8 * 4), 512, 131072, stream>>>(Wh, VT, ctx, kcp);
  } else {
    // r11 dense fallback
    cvt2_k<<<dim3(2 * B_ * QL_ * D_ / 8 / 256), 256, 0, stream>>>(Q, K, Qh, Kh);
    vt_k<<<dim3(KL_ / 32, D_ / 32, B_), 256, 0, stream>>>(V, VT);
    fgemm_k<true><<<dim3(B_ * 8 * 8), 512, 131072, stream>>>(Qh, Kh, nullptr,
                                                             Sh);
    softmax_k<false><<<dim3(B_ * QL_ / 4), 256, 0, stream>>>(
        Sh, W, Wh, mask, pad, nullptr, nullptr, nullptr);
    fgemm_k<false><<<dim3(B_ * 8 * 4), 512, 131072, stream>>>(Wh, VT, ctx,
                                                              nullptr);
  }
}

// Round 21
// 216.976 us; speedup vs baseline: 1.0203x; 1.0203x over previous
//
#include <hip/hip_runtime.h>
#include <hip/hip_fp16.h>

// Attention: ctx,W = softmax(Q K^T / 32 + mask, padmask) @ V
// B=8, QL=KL=2048, D=1024, fp32 I/O. fp16 MFMA internally (no fp32 MFMA on CDNA4).
// R12: PV K-compaction. R13/14: scores N-compaction. R15: fused cvt+vt.
// R16: qkc tail-tile split. R18/19: NT stores/loads for stream L2 hygiene.
// R21: revert R20 (mask-zero detection cost > saving; mask reads were
//      L3-absorbed). This is the R19 configuration -- session best 217 us.
#define B_ 8
#define QL_ 2048
#define KL_ 2048
#define D_ 1024

typedef _Float16 f16x8 __attribute__((ext_vector_type(8)));
typedef _Float16 f16x4 __attribute__((ext_vector_type(4)));
typedef float f32x4 __attribute__((ext_vector_type(4)));

// ---------------------------------------------------------------- async 16B
__device__ __forceinline__ void async16(const void* g, void* l) {
  __builtin_amdgcn_global_load_lds(
      (const __attribute__((address_space(1))) unsigned int*)g,
      (__attribute__((address_space(3))) unsigned int*)l, 16, 0, 0);
}

// ---------------------------------------------------------------- prefix scan
__global__ __launch_bounds__(256) void prep_k(const int* __restrict__ pad,
                                              int* __restrict__ pos,
                                              int* __restrict__ inv,
                                              int* __restrict__ kcp) {
  const int b = blockIdx.x;
  const int t = threadIdx.x;
  const int lane = t & 63, wv = t >> 6;
  __shared__ int wsum[4], wpre[4], kc_sh;
  const int* pr = pad + b * KL_;
  int* po = pos + b * KL_;
  int* iv = inv + b * KL_;
  int c[8], loc = 0;
#pragma unroll
  for (int j = 0; j < 8; ++j) {
    c[j] = (pr[t * 8 + j] == 0);
    loc += c[j];
  }
  int inc = loc;  // inclusive scan across the wave
  for (int d = 1; d < 64; d <<= 1) {
    int v = __shfl_up(inc, d);
    if (lane >= d) inc += v;
  }
  if (lane == 63) wsum[wv] = inc;
  __syncthreads();
  if (t == 0) {
    int acc = 0;
    for (int w = 0; w < 4; ++w) {
      wpre[w] = acc;
      acc += wsum[w];
    }
    kc_sh = acc;
    kcp[b] = (acc == 0) ? KL_ : acc;
  }
  __syncthreads();
  const int kc = kc_sh;
  int base = wpre[wv] + inc - loc;  // exclusive prefix for this thread
#pragma unroll
  for (int j = 0; j < 8; ++j) {
    const int k = t * 8 + j;
    if (kc == 0) {
      po[k] = k;
      iv[k] = k;
    } else {
      po[k] = base;
      if (c[j]) iv[base] = k;
    }
    base += c[j];
  }
}

// --------------------------------------------- fused cvt (Q,K) + V transpose
__global__ __launch_bounds__(256) void cvtvt_k(
    const float* __restrict__ Q, const float* __restrict__ K,
    const float* __restrict__ V, _Float16* __restrict__ Qh,
    _Float16* __restrict__ Khc, _Float16* __restrict__ VTc,
    const int* __restrict__ pad, const int* __restrict__ pos) {
  constexpr int CVT = B_ * QL_ * D_ / 8 / 256;  // 8192 blocks per tensor
  __shared__ float tile[32][33];
  const int id = blockIdx.x;
  if (id < 2 * CVT) {
    const bool isQ = id < CVT;
    const int i = (isQ ? id : id - CVT) * 256 + threadIdx.x;
    const f32x4* src = reinterpret_cast<const f32x4*>(isQ ? Q : K);
    const float scale = isQ ? 0.03125f : 1.0f;
    // Q/K are read exactly once -> bypass L2 (R19)
    f32x4 a = __builtin_nontemporal_load(src + i * 2);
    f32x4 b = __builtin_nontemporal_load(src + i * 2 + 1);
    f16x8 h;
    h[0] = (_Float16)(a[0] * scale); h[1] = (_Float16)(a[1] * scale);
    h[2] = (_Float16)(a[2] * scale); h[3] = (_Float16)(a[3] * scale);
    h[4] = (_Float16)(b[0] * scale); h[5] = (_Float16)(b[1] * scale);
    h[6] = (_Float16)(b[2] * scale); h[7] = (_Float16)(b[3] * scale);
    if (isQ) {
      reinterpret_cast<f16x8*>(Qh)[i] = h;
    } else {
      const int gk = (i * 8) >> 10;  // global K row (b*2048 + k)
      const int col8 = i & 127;      // 8-elem chunk within the row
      if (pad[gk] == 0) {
        const int b2 = gk >> 11;
        const int prow = pos[gk];  // packed row within batch
        reinterpret_cast<f16x8*>(Khc)[(size_t)(b2 << 11 | prow) * 128 + col8] =
            h;
      }
    }
  } else {
    const int vid = id - 2 * CVT;
    const int k0 = (vid & 63) * 32;         // KL/32 = 64
    const int d0 = ((vid >> 6) & 31) * 32;  // D/32 = 32
    const int b = vid >> 11;
    const float* Vb = V + (size_t)b * KL_ * D_;
    _Float16* VTb = VTc + (size_t)b * D_ * KL_;
    const int c = threadIdx.x & 31, r = threadIdx.x >> 5;
#pragma unroll
    for (int s = 0; s < 4; ++s)
      tile[r + s * 8][c] = __builtin_nontemporal_load(
          &Vb[(size_t)(k0 + r + s * 8) * D_ + d0 + c]);
    __syncthreads();
    const int kk = k0 + c;
    const int keep = (pad[b * KL_ + kk] == 0);
    const int col = pos[b * KL_ + kk];
#pragma unroll
    for (int s = 0; s < 4; ++s)
      if (keep)
        VTb[(size_t)(d0 + r + s * 8) * KL_ + col] =
            (_Float16)tile[c][r + s * 8];
  }
}

// ---------------------------------------------------------------- fallbacks
__global__ __launch_bounds__(256) void cvt2_k(const float* __restrict__ Q,
                                              const float* __restrict__ K,
                                              _Float16* __restrict__ Qh,
                                              _Float16* __restrict__ Kh) {
  constexpr int HALF = B_ * QL_ * D_ / 8 / 256;
  const bool isQ = blockIdx.x < HALF;
  const int i = (isQ ? blockIdx.x : blockIdx.x - HALF) * 256 + threadIdx.x;
  const float4* src = reinterpret_cast<const float4*>(isQ ? Q : K);
  const float scale = isQ ? 0.03125f : 1.0f;
  float4 a = src[i * 2], b = src[i * 2 + 1];
  f16x8 h;
  h[0] = (_Float16)(a.x * scale); h[1] = (_Float16)(a.y * scale);
  h[2] = (_Float16)(a.z * scale); h[3] = (_Float16)(a.w * scale);
  h[4] = (_Float16)(b.x * scale); h[5] = (_Float16)(b.y * scale);
  h[6] = (_Float16)(b.z * scale); h[7] = (_Float16)(b.w * scale);
  reinterpret_cast<f16x8*>(isQ ? Qh : Kh)[i] = h;
}

__global__ __launch_bounds__(256) void vt_k(const float* __restrict__ V,
                                            _Float16* __restrict__ VT) {
  __shared__ float tile[32][33];
  const int k0 = blockIdx.x * 32, d0 = blockIdx.y * 32, b = blockIdx.z;
  const float* Vb = V + (size_t)b * KL_ * D_;
  _Float16* VTb = VT + (size_t)b * D_ * KL_;
  const int c = threadIdx.x & 31, r = threadIdx.x >> 5;
#pragma unroll
  for (int s = 0; s < 4; ++s)
    tile[r + s * 8][c] = Vb[(size_t)(k0 + r + s * 8) * D_ + d0 + c];
  __syncthreads();
#pragma unroll
  for (int s = 0; s < 4; ++s)
    VTb[(size_t)(d0 + r + s * 8) * KL_ + k0 + c] = (_Float16)tile[c][r + s * 8];
}

// ---------------------------------------------------------------- dense GEMM
template <bool SCORES>
__global__ __launch_bounds__(512, 2) void fgemm_k(
    const _Float16* __restrict__ Ah, const _Float16* __restrict__ Bh,
    float* __restrict__ Cf, _Float16* __restrict__ Ch) {
  constexpr int Mc = 2048;
  constexpr int Nc = SCORES ? 2048 : 1024;
  constexpr int Kc = SCORES ? 1024 : 2048;
  constexpr int NIT = Kc / 64;
  constexpr int GX = Mc / 256, GY = Nc / 256;
  constexpr int CPX = B_ * GX * GY / 8;

  extern __shared__ char lds[];

  const int t = threadIdx.x;
  const int lane = t & 63;
  const int wid = t >> 6;
  const int wr = wid >> 2, wc = wid & 3;
  const int lo = lane & 15, hi = lane >> 4;

  const int id = blockIdx.x;
  const int swz = (id & 7) * CPX + (id >> 3);
  const int b = swz / (GX * GY);
  const int rem = swz % (GX * GY);
  const int m0 = (rem / GY) * 256, n0 = (rem % GY) * 256;

  const _Float16* Ab = Ah + (size_t)b * Mc * Kc;
  const _Float16* Bb = Bh + (size_t)b * Nc * Kc;

  int aoff[4], boff[4], ldst[4];
#pragma unroll
  for (int j = 0; j < 4; ++j) {
    const int row = j * 64 + wid * 8 + (lane >> 3);
    const int cg = (lane & 7) ^ (lane >> 3);
    aoff[j] = (m0 + row) * Kc + cg * 8;
    boff[j] = (n0 + row) * Kc + cg * 8;
    ldst[j] = j * 8192 + wid * 1024;
  }

  auto stage = [&](int it, int slot) {
    char* base = lds + slot * 65536;
    const int kb = it * 64;
#pragma unroll
    for (int j = 0; j < 4; ++j) {
      async16(Ab + aoff[j] + kb, base + ldst[j]);
      async16(Bb + boff[j] + kb, base + 32768 + ldst[j]);
    }
  };

  f32x4 acc[8][4];
#pragma unroll
  for (int m = 0; m < 8; ++m)
#pragma unroll
    for (int n = 0; n < 4; ++n)
#pragma unroll
      for (int i = 0; i < 4; ++i) acc[m][n][i] = 0.0f;

  int raf[8], rbf_[4];
#pragma unroll
  for (int m = 0; m < 8; ++m) {
    const int r = wr * 128 + m * 16 + lo;
    raf[m] = r * 128 + ((hi ^ (r & 7)) << 4);
  }
#pragma unroll
  for (int n = 0; n < 4; ++n) {
    const int r = wc * 64 + n * 16 + lo;
    rbf_[n] = r * 128 + ((hi ^ (r & 7)) << 4);
  }

  auto compute = [&](int slot) {
    const char* Ac = lds + slot * 65536;
    const char* Bc = Ac + 32768;
#pragma unroll
    for (int kh = 0; kh < 2; ++kh) {
      const int kx = kh * 64;
      f16x8 af[8], bfr[4];
#pragma unroll
      for (int m = 0; m < 8; ++m)
        af[m] = *reinterpret_cast<const f16x8*>(Ac + (raf[m] ^ kx));
#pragma unroll
      for (int n = 0; n < 4; ++n)
        bfr[n] = *reinterpret_cast<const f16x8*>(Bc + (rbf_[n] ^ kx));
      __builtin_amdgcn_s_setprio(1);
#pragma unroll
      for (int m = 0; m < 8; ++m)
#pragma unroll
        for (int n = 0; n < 4; ++n)
          acc[m][n] = __builtin_amdgcn_mfma_f32_16x16x32_f16(
              af[m], bfr[n], acc[m][n], 0, 0, 0);
      __builtin_amdgcn_s_setprio(0);
    }
  };

  stage(0, 0);
  for (int it = 0; it < NIT; ++it) {
    asm volatile("s_waitcnt vmcnt(0) lgkmcnt(0)" ::: "memory");
    __builtin_amdgcn_sched_barrier(0);
    __builtin_amdgcn_s_barrier();
    if (it + 1 < NIT) stage(it + 1, (it + 1) & 1);
    compute(it & 1);
  }

  if constexpr (SCORES) {
    _Float16* Cb = Ch + (size_t)b * Mc * Nc;
#pragma unroll
    for (int n = 0; n < 4; ++n) {
      const int col = n0 + wc * 64 + n * 16 + lo;
#pragma unroll
      for (int m = 0; m < 8; ++m) {
        const int r0 = m0 + wr * 128 + m * 16 + hi * 4;
#pragma unroll
        for (int i = 0; i < 4; ++i)
          Cb[(size_t)(r0 + i) * Nc + col] = (_Float16)acc[m][n][i];
      }
    }
  } else {
    float* Cb = Cf + (size_t)b * Mc * Nc;
#pragma unroll
    for (int n = 0; n < 4; ++n) {
      const int col = n0 + wc * 64 + n * 16 + lo;
#pragma unroll
      for (int m = 0; m < 8; ++m) {
        const int r0 = m0 + wr * 128 + m * 16 + hi * 4;
#pragma unroll
        for (int i = 0; i < 4; ++i)
          __builtin_nontemporal_store(acc[m][n][i],
                                      &Cb[(size_t)(r0 + i) * Nc + col]);
      }
    }
  }
}

// ---------------------------------------------------------------- compact QK
__global__ __launch_bounds__(512, 2) void fgemm_qkc(
    const _Float16* __restrict__ Qh, const _Float16* __restrict__ Khc,
    _Float16* __restrict__ Sh, const int* __restrict__ inv,
    const int* __restrict__ kcp) {
  constexpr int Kc = 1024;
  constexpr int NIT = Kc / 64;

  extern __shared__ char lds[];

  const int t = threadIdx.x;
  const int lane = t & 63;
  const int wid = t >> 6;
  const int lo = lane & 15, hi = lane >> 4;
  const int id = blockIdx.x;

  if (id < 256) {
    // ---------------- main: 256x256 tile, quadrants 0..3
    const int wr = wid >> 2, wc = wid & 3;
    const int b = id & 7;
    const int n0 = ((id >> 3) & 3) * 256;
    const int m0 = ((id >> 5) & 7) * 256;

    const int kc = kcp[b];
    if (n0 >= ((kc + 63) & ~63)) return;

    const _Float16* Ab = Qh + (size_t)b * 2048 * Kc;
    const _Float16* Bb = Khc + (size_t)b * 2048 * Kc;

    int aoff[4], boff[4], ldst[4];
#pragma unroll
    for (int j = 0; j < 4; ++j) {
      const int row = j * 64 + wid * 8 + (lane >> 3);
      const int cg = (lane & 7) ^ (lane >> 3);
      aoff[j] = (m0 + row) * Kc + cg * 8;
      boff[j] = (n0 + row) * Kc + cg * 8;
      ldst[j] = j * 8192 + wid * 1024;
    }

    auto stage = [&](int it, int slot) {
      char* base = lds + slot * 65536;
      const int kb = it * 64;
#pragma unroll
      for (int j = 0; j < 4; ++j) {
        async16(Ab + aoff[j] + kb, base + ldst[j]);
        async16(Bb + boff[j] + kb, base + 32768 + ldst[j]);
      }
    };

    f32x4 acc[8][4];
#pragma unroll
    for (int m2 = 0; m2 < 8; ++m2)
#pragma unroll
      for (int n = 0; n < 4; ++n)
#pragma unroll
        for (int i = 0; i < 4; ++i) acc[m2][n][i] = 0.0f;

    int raf[8], rbf_[4];
#pragma unroll
    for (int m2 = 0; m2 < 8; ++m2) {
      const int r = wr * 128 + m2 * 16 + lo;
      raf[m2] = r * 128 + ((hi ^ (r & 7)) << 4);
    }
#pragma unroll
    for (int n = 0; n < 4; ++n) {
      const int r = wc * 64 + n * 16 + lo;
      rbf_[n] = r * 128 + ((hi ^ (r & 7)) << 4);
    }

    auto compute = [&](int slot) {
      const char* Ac = lds + slot * 65536;
      const char* Bc = Ac + 32768;
#pragma unroll
      for (int kh = 0; kh < 2; ++kh) {
        const int kx = kh * 64;
        f16x8 af[8], bfr[4];
#pragma unroll
        for (int m2 = 0; m2 < 8; ++m2)
          af[m2] = *reinterpret_cast<const f16x8*>(Ac + (raf[m2] ^ kx));
#pragma unroll
        for (int n = 0; n < 4; ++n)
          bfr[n] = *reinterpret_cast<const f16x8*>(Bc + (rbf_[n] ^ kx));
        __builtin_amdgcn_s_setprio(1);
#pragma unroll
        for (int m2 = 0; m2 < 8; ++m2)
#pragma unroll
          for (int n = 0; n < 4; ++n)
            acc[m2][n] = __builtin_amdgcn_mfma_f32_16x16x32_f16(
                af[m2], bfr[n], acc[m2][n], 0, 0, 0);
        __builtin_amdgcn_s_setprio(0);
      }
    };

    stage(0, 0);
    for (int it = 0; it < NIT; ++it) {
      asm volatile("s_waitcnt vmcnt(0) lgkmcnt(0)" ::: "memory");
      __builtin_amdgcn_sched_barrier(0);
      __builtin_amdgcn_s_barrier();
      if (it + 1 < NIT) stage(it + 1, (it + 1) & 1);
      compute(it & 1);
    }

    _Float16* Cb = Sh + (size_t)b * 2048 * 2048;
    const int* ivb = inv + b * KL_;
#pragma unroll
    for (int n = 0; n < 4; ++n) {
      const int ccol = n0 + wc * 64 + n * 16 + lo;
      if (ccol < kc) {
        const int dcol = ivb[ccol];
#pragma unroll
        for (int m2 = 0; m2 < 8; ++m2) {
          const int r0 = m0 + wr * 128 + m2 * 16 + hi * 4;
#pragma unroll
          for (int i = 0; i < 4; ++i)
            Cb[(size_t)(r0 + i) * 2048 + dcol] = (_Float16)acc[m2][n][i];
        }
      }
    }
  } else {
    // ---------------- tail: 128x64 tile, n0 >= 1024
    const int tid = id - 256;
    const int b = tid & 7;
    const int m0 = ((tid >> 3) & 15) * 128;
    const int n0 = 1024 + ((tid >> 7) & 15) * 64;

    const int kc = kcp[b];
    if (n0 >= ((kc + 63) & ~63)) return;

    const _Float16* Ab = Qh + (size_t)b * 2048 * Kc;
    const _Float16* Bb = Khc + (size_t)b * 2048 * Kc;

    const int cg = (lane & 7) ^ (lane >> 3);
    int aoff[2], ldstA[2];
#pragma unroll
    for (int j = 0; j < 2; ++j) {
      const int row = j * 64 + wid * 8 + (lane >> 3);
      aoff[j] = (m0 + row) * Kc + cg * 8;
      ldstA[j] = j * 8192 + wid * 1024;
    }
    const int boff0 = (n0 + wid * 8 + (lane >> 3)) * Kc + cg * 8;

    auto stage = [&](int it, int slot) {
      char* base = lds + slot * 32768;
      const int kb = it * 64;
      async16(Ab + aoff[0] + kb, base + ldstA[0]);
      async16(Ab + aoff[1] + kb, base + ldstA[1]);
      async16(Bb + boff0 + kb, base + 16384 + wid * 1024);
    };

    f32x4 acc[4];
#pragma unroll
    for (int n = 0; n < 4; ++n)
#pragma unroll
      for (int i = 0; i < 4; ++i) acc[n][i] = 0.0f;

    int rafm;
    {
      const int r = wid * 16 + lo;
      rafm = r * 128 + ((hi ^ (r & 7)) << 4);
    }
    int rbf2[4];
#pragma unroll
    for (int n = 0; n < 4; ++n) {
      const int r = n * 16 + lo;
      rbf2[n] = r * 128 + ((hi ^ (r & 7)) << 4);
    }

    auto compute = [&](int slot) {
      const char* Ac = lds + slot * 32768;
      const char* Bc = Ac + 16384;
#pragma unroll
      for (int kh = 0; kh < 2; ++kh) {
        const int kx = kh * 64;
        f16x8 af = *reinterpret_cast<const f16x8*>(Ac + (rafm ^ kx));
        f16x8 bfr[4];
#pragma unroll
        for (int n = 0; n < 4; ++n)
          bfr[n] = *reinterpret_cast<const f16x8*>(Bc + (rbf2[n] ^ kx));
        __builtin_amdgcn_s_setprio(1);
#pragma unroll
        for (int n = 0; n < 4; ++n)
          acc[n] = __builtin_amdgcn_mfma_f32_16x16x32_f16(af, bfr[n], acc[n],
                                                          0, 0, 0);
        __builtin_amdgcn_s_setprio(0);
      }
    };

    stage(0, 0);
    for (int it = 0; it < NIT; ++it) {
      asm volatile("s_waitcnt vmcnt(0) lgkmcnt(0)" ::: "memory");
      __builtin_amdgcn_sched_barrier(0);
      __builtin_amdgcn_s_barrier();
      if (it + 1 < NIT) stage(it + 1, (it + 1) & 1);
      compute(it & 1);
    }

    _Float16* Cb = Sh + (size_t)b * 2048 * 2048;
    const int* ivb = inv + b * KL_;
#pragma unroll
    for (int n = 0; n < 4; ++n) {
      const int ccol = n0 + n * 16 + lo;
      if (ccol < kc) {
        const int dcol = ivb[ccol];
        const int r0 = m0 + wid * 16 + hi * 4;
#pragma unroll
        for (int i = 0; i < 4; ++i)
          Cb[(size_t)(r0 + i) * 2048 + dcol] = (_Float16)acc[n][i];
      }
    }
  }
}

// ---------------------------------------------------------------- compact PV
__global__ __launch_bounds__(512, 2) void fgemm_pv(
    const _Float16* __restrict__ Whc, const _Float16* __restrict__ VTc,
    float* __restrict__ Cf, const int* __restrict__ kcp) {
  constexpr int Mc = 2048, Nc = 1024;
  constexpr int GX = 8, GY = 4;
  constexpr int CPX = B_ * GX * GY / 8;

  extern __shared__ char lds[];

  const int t = threadIdx.x;
  const int lane = t & 63;
  const int wid = t >> 6;
  const int wr = wid >> 2, wc = wid & 3;
  const int lo = lane & 15, hi = lane >> 4;

  const int id = blockIdx.x;
  const int swz = (id & 7) * CPX + (id >> 3);
  const int b = swz / (GX * GY);
  const int rem = swz % (GX * GY);
  const int m0 = (rem / GY) * 256, n0 = (rem % GY) * 256;

  const int kc = kcp[b];
  const int KA = (kc + 63) & ~63;
  const int NIT = KA >> 6;

  const _Float16* Ab = Whc + (size_t)b * 2048 * 2048;
  const _Float16* Bb = VTc + (size_t)b * Nc * KL_;

  int aoff[4], boff[4], ldst[4];
#pragma unroll
  for (int j = 0; j < 4; ++j) {
    const int row = j * 64 + wid * 8 + (lane >> 3);
    const int cg = (lane & 7) ^ (lane >> 3);
    aoff[j] = (m0 + row) * KA + cg * 8;
    boff[j] = (n0 + row) * KL_ + cg * 8;
    ldst[j] = j * 8192 + wid * 1024;
  }

  auto stage = [&](int it, int slot) {
    char* base = lds + slot * 65536;
    const int kb = it * 64;
#pragma unroll
    for (int j = 0; j < 4; ++j) {
      async16(Ab + aoff[j] + kb, base + ldst[j]);
      async16(Bb + boff[j] + kb, base + 32768 + ldst[j]);
    }
  };

  f32x4 acc[8][4];
#pragma unroll
  for (int m = 0; m < 8; ++m)
#pragma unroll
    for (int n = 0; n < 4; ++n)
#pragma unroll
      for (int i = 0; i < 4; ++i) acc[m][n][i] = 0.0f;

  int raf[8], rbf_[4];
#pragma unroll
  for (int m = 0; m < 8; ++m) {
    const int r = wr * 128 + m * 16 + lo;
    raf[m] = r * 128 + ((hi ^ (r & 7)) << 4);
  }
#pragma unroll
  for (int n = 0; n < 4; ++n) {
    const int r = wc * 64 + n * 16 + lo;
    rbf_[n] = r * 128 + ((hi ^ (r & 7)) << 4);
  }

  auto compute = [&](int slot) {
    const char* Ac = lds + slot * 65536;
    const char* Bc = Ac + 32768;
#pragma unroll
    for (int kh = 0; kh < 2; ++kh) {
      const int kx = kh * 64;
      f16x8 af[8], bfr[4];
#pragma unroll
      for (int m = 0; m < 8; ++m)
        af[m] = *reinterpret_cast<const f16x8*>(Ac + (raf[m] ^ kx));
#pragma unroll
      for (int n = 0; n < 4; ++n)
        bfr[n] = *reinterpret_cast<const f16x8*>(Bc + (rbf_[n] ^ kx));
      __builtin_amdgcn_s_setprio(1);
#pragma unroll
      for (int m = 0; m < 8; ++m)
#pragma unroll
        for (int n = 0; n < 4; ++n)
          acc[m][n] = __builtin_amdgcn_mfma_f32_16x16x32_f16(
              af[m], bfr[n], acc[m][n], 0, 0, 0);
      __builtin_amdgcn_s_setprio(0);
    }
  };

  stage(0, 0);
  for (int it = 0; it < NIT; ++it) {
    asm volatile("s_waitcnt vmcnt(0) lgkmcnt(0)" ::: "memory");
    __builtin_amdgcn_sched_barrier(0);
    __builtin_amdgcn_s_barrier();
    if (it + 1 < NIT) stage(it + 1, (it + 1) & 1);
    compute(it & 1);
  }

  float* Cb = Cf + (size_t)b * Mc * Nc;
#pragma unroll
  for (int n = 0; n < 4; ++n) {
    const int col = n0 + wc * 64 + n * 16 + lo;
#pragma unroll
    for (int m = 0; m < 8; ++m) {
      const int r0 = m0 + wr * 128 + m * 16 + hi * 4;
#pragma unroll
      for (int i = 0; i < 4; ++i)
        __builtin_nontemporal_store(acc[m][n][i],
                                    &Cb[(size_t)(r0 + i) * Nc + col]);
    }
  }
}

// ---------------------------------------------------------------- row softmax
template <bool COMPACT>
__global__ __launch_bounds__(256) void softmax_k(
    const _Float16* __restrict__ Sh, float* __restrict__ W,
    _Float16* __restrict__ Wh, const float* __restrict__ mask,
    const int* __restrict__ pad, const int* __restrict__ pos,
    const int* __restrict__ kcp) {
  const int row = blockIdx.x * 4 + (threadIdx.x >> 6);
  const int lane = threadIdx.x & 63;
  const int b = row >> 11, q = row & 2047;
  const f16x4* Sr = reinterpret_cast<const f16x4*>(Sh + (size_t)row * KL_);
  f32x4* Wr = reinterpret_cast<f32x4*>(W + (size_t)row * KL_);
  const float4* Mr = reinterpret_cast<const float4*>(mask + (size_t)q * KL_);
  const int4* Pr = reinterpret_cast<const int4*>(pad + (size_t)b * KL_);
  int4 pk[8];
  float4 v[8];
#pragma unroll
  for (int s = 0; s < 8; ++s) {
    // S' is read exactly once (then dead) -> bypass L2 (R19)
    f16x4 sv = __builtin_nontemporal_load(&Sr[s * 64 + lane]);
    float4 mk = Mr[s * 64 + lane];
    int4 p = Pr[s * 64 + lane];
    pk[s] = p;
    float4 x;
    x.x = p.x ? -1e12f : (float)sv[0] + mk.x;
    x.y = p.y ? -1e12f : (float)sv[1] + mk.y;
    x.z = p.z ? -1e12f : (float)sv[2] + mk.z;
    x.w = p.w ? -1e12f : (float)sv[3] + mk.w;
    v[s] = x;
  }
  float mx = -3.402823466e38f;
#pragma unroll
  for (int s = 0; s < 8; ++s)
    mx = fmaxf(mx, fmaxf(fmaxf(v[s].x, v[s].y), fmaxf(v[s].z, v[s].w)));
#pragma unroll
  for (int off = 32; off > 0; off >>= 1) mx = fmaxf(mx, __shfl_xor(mx, off));
  float sum = 0.0f;
#pragma unroll
  for (int s = 0; s < 8; ++s) {
    v[s].x = __expf(v[s].x - mx);
    v[s].y = __expf(v[s].y - mx);
    v[s].z = __expf(v[s].z - mx);
    v[s].w = __expf(v[s].w - mx);
    sum += v[s].x + v[s].y + v[s].z + v[s].w;
  }
#pragma unroll
  for (int off = 32; off > 0; off >>= 1) sum += __shfl_xor(sum, off);
  const float inv = 1.0f / sum;

  if constexpr (COMPACT) {
    const int kc = kcp[b];
    const int kcpad = (kc + 63) & ~63;
    _Float16* Wc = Wh + (size_t)b * 2048 * 2048 + (size_t)q * kcpad;
    const int4* Po = reinterpret_cast<const int4*>(pos + (size_t)b * KL_);
#pragma unroll
    for (int s = 0; s < 8; ++s) {
      f32x4 o;
      o[0] = v[s].x * inv;
      o[1] = v[s].y * inv;
      o[2] = v[s].z * inv;
      o[3] = v[s].w * inv;
      // W is a terminal output (never re-read) -> bypass L2 (R18)
      __builtin_nontemporal_store(o, &Wr[s * 64 + lane]);
      int4 ps = Po[s * 64 + lane];
      if (!pk[s].x) Wc[ps.x] = (_Float16)o[0];
      if (!pk[s].y) Wc[ps.y] = (_Float16)o[1];
      if (!pk[s].z) Wc[ps.z] = (_Float16)o[2];
      if (!pk[s].w) Wc[ps.w] = (_Float16)o[3];
    }
    if (kc + lane < kcpad) Wc[kc + lane] = (_Float16)0.0f;  // zero tail
  } else {
    f16x4* Whr = reinterpret_cast<f16x4*>(Wh + (size_t)row * KL_);
#pragma unroll
    for (int s = 0; s < 8; ++s) {
      f32x4 o;
      o[0] = v[s].x * inv;
      o[1] = v[s].y * inv;
      o[2] = v[s].z * inv;
      o[3] = v[s].w * inv;
      __builtin_nontemporal_store(o, &Wr[s * 64 + lane]);
      f16x4 h;
      h[0] = (_Float16)o[0];
      h[1] = (_Float16)o[1];
      h[2] = (_Float16)o[2];
      h[3] = (_Float16)o[3];
      Whr[s * 64 + lane] = h;
    }
  }
}

// ---------------------------------------------------------------- launch
extern "C" void kernel_launch(void* const* d_in, const int* in_sizes, int n_in,
                              void* d_out, int out_size, void* d_ws,
                              size_t ws_size, hipStream_t stream) {
  const float* Q = (const float*)d_in[0];
  const float* K = (const float*)d_in[1];
  const float* V = (const float*)d_in[2];
  const float* mask = (const float*)d_in[3];
  const int* pad = (const int*)d_in[4];

  float* ctx = (float*)d_out;              // [8][2048][1024] fp32 (final)
  float* W = ctx + (size_t)B_ * QL_ * D_;  // [8][2048][2048] fp32 (final)
  _Float16* Sh = (_Float16*)d_out;         // S' fp16 reuses ctx region

  const size_t MB = 1024 * 1024;
  _Float16* VT = (_Float16*)d_ws;                     // 32 MiB
  _Float16* Qh = (_Float16*)((char*)d_ws + 32 * MB);  // 32 MiB
  _Float16* Kh = (_Float16*)((char*)d_ws + 64 * MB);  // 32 MiB (packed Khc)
  _Float16* Wh = Qh;                                  // 64 MiB, reused post-QK

  (void)hipFuncSetAttribute((const void*)fgemm_k<true>,
                            hipFuncAttributeMaxDynamicSharedMemorySize, 131072);
  (void)hipFuncSetAttribute((const void*)fgemm_k<false>,
                            hipFuncAttributeMaxDynamicSharedMemorySize, 131072);
  (void)hipFuncSetAttribute((const void*)fgemm_qkc,
                            hipFuncAttributeMaxDynamicSharedMemorySize, 131072);
  (void)hipFuncSetAttribute((const void*)fgemm_pv,
                            hipFuncAttributeMaxDynamicSharedMemorySize, 131072);

  const bool compact = ws_size >= 96 * MB + (1 << 18);
  if (compact) {
    int* pos = (int*)((char*)d_ws + 96 * MB);  // [8][2048] = 64 KiB
    int* inv = pos + B_ * KL_;                 // [8][2048] = 64 KiB
    int* kcp = inv + B_ * KL_;                 // [8]
    prep_k<<<dim3(B_), 256, 0, stream>>>(pad, pos, inv, kcp);
    cvtvt_k<<<dim3(2 * 8192 + 64 * 32 * B_), 256, 0, stream>>>(
        Q, K, V, Qh, Kh, VT, pad, pos);
    fgemm_qkc<<<dim3(256 + 2048), 512, 131072, stream>>>(Qh, Kh, Sh, inv, kcp);
    softmax_k<true><<<dim3(B_ * QL_ / 4), 256, 0, stream>>>(Sh, W, Wh, mask,
                                                            pad, pos, kcp);
    fgemm_pv<<<dim3(B_ * 8 * 4), 512, 131072, stream>>>(Wh, VT, ctx, kcp);
  } else {
    // r11 dense fallback
    cvt2_k<<<dim3(2 * B_ * QL_ * D_ / 8 / 256), 256, 0, stream>>>(Q, K, Qh, Kh);
    vt_k<<<dim3(KL_ / 32, D_ / 32, B_), 256, 0, stream>>>(V, VT);
    fgemm_k<true><<<dim3(B_ * 8 * 8), 512, 131072, stream>>>(Qh, Kh, nullptr,
                                                             Sh);
    softmax_k<false><<<dim3(B_ * QL_ / 4), 256, 0, stream>>>(
        Sh, W, Wh, mask, pad, nullptr, nullptr);
    fgemm_k<false><<<dim3(B_ * 8 * 4), 512, 131072, stream>>>(Wh, VT, ctx,
                                                              nullptr);
  }
}